// Round 8
// baseline (222.158 us; speedup 1.0000x reference)
//
#include <hip/hip_runtime.h>

#define B_     8
#define LV_    4096
#define D_     256
#define N_     2048
#define P_     32
#define WROWS_ 64                      // rows per LDS window (64 KB tile)
#define NWIN_  (B_ * (LV_ / WROWS_))   // 512 (batch,window) keys
#define NBINS_ (N_ * P_)               // 65536
#define CAP_   256                     // bucket capacity per window (mean 128)
#define CPB_   32                      // bins per block segment
#define SEGS_  (CAP_ / CPB_)           // 8
#define NGW_   (NWIN_ * SEGS_)         // 4096 window-blocks
#define NOVF_  64                      // overflow blocks (normally instant-exit)

typedef float v4f __attribute__((ext_vector_type(4)));

__device__ __forceinline__ float lane_bcast_f(float v, int l) {
    return __int_as_float(__builtin_amdgcn_readlane(__float_as_int(v), l));
}

// First row touched by bin (n,p) — same clamping as the main math. Used only
// for window ASSIGNMENT (performance); the per-row interval clamps in
// process_bin guarantee correctness for any assignment.
__device__ __forceinline__ int bin_r_first(const float* __restrict__ boxes, int n, int p) {
    const float y1 = boxes[2 * n], y2 = boxes[2 * n + 1];
    const float bin_h = (y2 - y1) * (1.0f / (float)P_);
    const int gh = (int)ceilf(bin_h);
    if (gh < 1) return 0;
    const float sub  = bin_h / (float)gh;
    const float boff = (y1 - 0.5f) + (float)p * bin_h;
    const float a    = fmaf(0.5f, sub, boff);
    int r = (int)floorf(a);
    if (r < 0) r = 0;
    if (r > LV_ - 1) r = LV_ - 1;
    return r;
}

// ---- R8 pre-pass: ONE scatter kernel into fixed-capacity buckets.
// R7's count+scan+scatter chain was ~40us of launch overhead (4 tiny serial
// dispatches at ~10us each). Buckets need no scan: slot from atomicAdd;
// window identity is recovered from the bucket INDEX in the win kernel.
// Overflow (slot>=CAP_, impossible-in-practice: mean 128/window) goes to an
// overflow list handled by tile-less blocks -> data-independent correctness.
__global__ __launch_bounds__(256) void scatter_bins_kernel(
    const float* __restrict__ boxes, const int* __restrict__ batch_idx,
    int* __restrict__ wsp)
{
    int* cnt    = wsp;               // [512]
    int* ovfc   = wsp + NWIN_;       // [1]
    int* bucket = wsp + 1024;        // [NWIN_ * CAP_]
    int* ovf    = bucket + NWIN_ * CAP_;  // [NBINS_]
    const int idx = blockIdx.x * 256 + threadIdx.x;
    const int n = idx >> 5, p = idx & 31;
    const int key = (batch_idx[n] << 6) | (bin_r_first(boxes, n, p) >> 6);
    const int slot = atomicAdd(&cnt[key], 1);
    if (slot < CAP_) bucket[key * CAP_ + slot] = idx;
    else             ovf[atomicAdd(ovfc, 1)] = idx;
}

// Per-bin accumulation: identical math to R5/R7 (same absmax). Reads rows
// from the LDS tile where the interval [wlo, wlo+WROWS_) covers them, global
// otherwise. tile==nullptr -> pure-global path (overflow blocks).
__device__ __forceinline__ void process_bin(
    const float* __restrict__ feat, const float* __restrict__ boxes,
    const int* __restrict__ batch_idx, float* __restrict__ out,
    const v4f* tile, int wb, int wlo, int idx, int lane)
{
    const int n = idx >> 5, p = idx & 31;
    const int bi = __builtin_amdgcn_readfirstlane(batch_idx[n]);

    const float y1 = boxes[2 * n], y2 = boxes[2 * n + 1];
    const float bin_h = (y2 - y1) * (1.0f / (float)P_);
    const int gh = (int)ceilf(bin_h);

    const v4f* prow = (const v4f*)feat + (long)bi * (LV_ * (D_ / 4));
    v4f acc0 = {0.f,0.f,0.f,0.f}, acc1 = {0.f,0.f,0.f,0.f};

    if (gh >= 1) {
        const float cntf = (float)gh, sub = bin_h / cntf, inv_sub = 1.0f / sub;
        const float halfsub = 0.5f * sub;
        const float boff = (y1 - 0.5f) + (float)p * bin_h;
        const float a = fmaf(0.5f, sub, boff), ylast = fmaf(cntf - 0.5f, sub, boff);

        int r_first = (int)floorf(a);
        if (r_first < 0) r_first = 0; if (r_first > LV_-1) r_first = LV_-1;
        int r_last = (int)floorf(ylast) + 1;
        if (r_last > LV_-1) r_last = LV_-1; if (r_last < r_first) r_last = r_first;
        const int r0 = __builtin_amdgcn_readfirstlane(r_first);
        const int rl = __builtin_amdgcn_readfirstlane(r_last);
        const float lanef = (float)lane;

        for (int gbase = r0; gbase <= rl; gbase += 64) {
            int kmax = rl - gbase; if (kmax > 63) kmax = 63;

            // lane-parallel closed-form weights (2nd difference of prefix area)
            const int   r  = gbase + lane;
            const float d0 = ((float)gbase + lanef) - a;
            const float dm = d0 - 1.0f, dp = d0 + 1.0f;
            const float nm = fminf(fmaxf(ceilf(dm * inv_sub), 0.0f), cntf);
            const float n0 = fminf(fmaxf(ceilf(d0 * inv_sub), 0.0f), cntf);
            const float np = fminf(fmaxf(ceilf(dp * inv_sub), 0.0f), cntf);
            float Pm = fmaf(nm, dm, -halfsub * fmaf(nm, nm, -nm));
            float P0 = fmaf(n0, d0, -halfsub * fmaf(n0, n0, -n0));
            float Pp = fmaf(np, dp, -halfsub * fmaf(np, np, -np));
            if (r == 0)       Pm = P0;
            if (r == LV_ - 1) Pp = P0 + cntf;
            const float Wl = (Pm + Pp) - 2.0f * P0;

            // split k-range into [0,lo) global | [lo,hi) LDS | [hi,t) global
            const int t = kmax + 1;
            int lo, hi;
            if (tile && bi == wb) {
                lo = wlo - gbase;          lo = lo < 0 ? 0 : (lo > t ? t : lo);
                hi = wlo + WROWS_ - gbase; hi = hi < lo ? lo : (hi > t ? t : hi);
            } else { lo = t; hi = t; }

#define GSEG(KS, KE) do {                                                        \
    int k = (KS);                                                                \
    const v4f* pS = prow + (long)(gbase + k) * (D_ / 4);                         \
    for (; k + 4 <= (KE); k += 4) {                                              \
        v4f v0 = pS[lane], v1 = pS[lane+64], v2 = pS[lane+128], v3 = pS[lane+192];\
        acc0 += v0 * lane_bcast_f(Wl, k);   acc1 += v1 * lane_bcast_f(Wl, k+1);  \
        acc0 += v2 * lane_bcast_f(Wl, k+2); acc1 += v3 * lane_bcast_f(Wl, k+3);  \
        pS += 4 * (D_ / 4); }                                                    \
    for (; k < (KE); ++k) { v4f v = pS[lane]; acc0 += v * lane_bcast_f(Wl, k); pS += (D_ / 4); } \
} while (0)

            GSEG(0, lo);                               // prefix (usually empty)
            {                                          // LDS mid-segment
                int k = lo;
                const v4f* tp = tile + (gbase + lo - wlo) * 64 + lane;
                for (; k + 4 <= hi; k += 4) {
                    v4f t0 = tp[0], t1 = tp[64], t2 = tp[128], t3 = tp[192];
                    acc0 += t0 * lane_bcast_f(Wl, k);   acc1 += t1 * lane_bcast_f(Wl, k+1);
                    acc0 += t2 * lane_bcast_f(Wl, k+2); acc1 += t3 * lane_bcast_f(Wl, k+3);
                    tp += 256;
                }
                for (; k < hi; ++k) { acc0 += tp[0] * lane_bcast_f(Wl, k); tp += 64; }
            }
            GSEG(hi, t);                               // suffix overhang
#undef GSEG
        }
    }

    const float inv_c = 1.0f / (float)(gh > 1 ? gh : 1);
    v4f res = (acc0 + acc1) * inv_c;
    v4f* op = (v4f*)out + ((long)n * P_ + p) * (D_ / 4) + lane;
    __builtin_nontemporal_store(res, op);
}

// Main kernel: block = one 32-bin segment of one window's bucket + 64-row
// LDS tile. Window identity from block index (no sorted list needed).
// Blocks >= NGW_ drain the overflow list tile-less (normally empty).
__global__ __launch_bounds__(512) void roi_win_kernel(
    const float* __restrict__ feat, const float* __restrict__ boxes,
    const int* __restrict__ batch_idx, const int* __restrict__ wsp,
    float* __restrict__ out)
{
    __shared__ v4f tile[WROWS_ * 64];                  // 64 KB -> 2 blocks/CU
    const int* cnt    = wsp;
    const int* ovfc   = wsp + NWIN_;
    const int* bucket = wsp + 1024;
    const int* ovf    = bucket + NWIN_ * CAP_;

    const int tid  = threadIdx.x;
    const int lane = tid & 63;
    const int wv   = tid >> 6;                         // wave 0..7
    const int bid  = blockIdx.x;

    if (bid >= NGW_) {                                 // ---- overflow path ----
        const int no = ovfc[0];
        for (int j = (bid - NGW_) * 8 + wv; j < no; j += NOVF_ * 8) {
            const int idx = __builtin_amdgcn_readfirstlane(ovf[j]);
            process_bin(feat, boxes, batch_idx, out, nullptr, 0, 0, idx, lane);
        }
        return;
    }

    // bijective XCD swizzle: XCD x gets blk in [512x,512x+512) -> w in
    // [64x,64x+64) -> exactly batch x resident in its own L2.
    const int blk = (bid & 7) * (NGW_ / 8) + (bid >> 3);
    const int w   = blk >> 3;                          // window key (b<<6)|win
    const int seg = blk & (SEGS_ - 1);

    const int total = min(cnt[w], CAP_);
    const int start = seg * CPB_;
    if (start >= total) return;                        // block-uniform quick-exit
    const int nb = min(CPB_, total - start);

    const int wb  = w >> 6;
    const int wlo = (w & 63) << 6;

    // ---- stage window: 8 waves x 8 rows, direct global->LDS (lane*16B)
    {
        const int r0 = wv * 8;
        const float* srow = feat + ((long)wb * LV_ + wlo + r0) * D_ + lane * 4;
        v4f* lrow = tile + r0 * 64;
#if __has_builtin(__builtin_amdgcn_global_load_lds)
        #pragma unroll
        for (int j = 0; j < 8; ++j) {
            __builtin_amdgcn_global_load_lds(
                (const __attribute__((address_space(1))) void*)(srow + j * D_),
                (__attribute__((address_space(3))) void*)(lrow + j * 64),
                16, 0, 0);
        }
#else
        const v4f* src = (const v4f*)feat + ((long)wb * LV_ + wlo + r0) * (D_ / 4) + lane;
        v4f t0 = src[0],   t1 = src[64],  t2 = src[128], t3 = src[192];
        v4f t4 = src[256], t5 = src[320], t6 = src[384], t7 = src[448];
        v4f* dst = lrow + lane;
        dst[0]   = t0; dst[64]  = t1; dst[128] = t2; dst[192] = t3;
        dst[256] = t4; dst[320] = t5; dst[384] = t6; dst[448] = t7;
#endif
    }
    __syncthreads();                                   // drains vmcnt+lgkmcnt

    for (int i = wv; i < nb; i += 8) {
        const int idx = __builtin_amdgcn_readfirstlane(bucket[w * CAP_ + start + i]);
        process_bin(feat, boxes, batch_idx, out, tile, wb, wlo, idx, lane);
    }
}

// ---------------- fallback path (R5 kernels, used when ws too small) --------
__global__ __launch_bounds__(256) void build_order_kernel(
    const int* __restrict__ batch_idx, int* __restrict__ order)
{
    __shared__ int cnt[B_], cur[B_];
    const int tid = threadIdx.x;
    if (tid < B_) cnt[tid] = 0;
    __syncthreads();
    for (int n = tid; n < N_; n += 256) atomicAdd(&cnt[batch_idx[n]], 1);
    __syncthreads();
    if (tid == 0) { int s = 0; for (int b = 0; b < B_; ++b) { cur[b] = s; s += cnt[b]; } }
    __syncthreads();
    for (int n = tid; n < N_; n += 256)
        order[atomicAdd(&cur[batch_idx[n]], 1)] = n;
}

__global__ __launch_bounds__(256) void roi_rows_kernel(
    const float* __restrict__ feat, const float* __restrict__ boxes,
    const int* __restrict__ batch_idx, const int* __restrict__ order,
    float* __restrict__ out)
{
    const int nwg = (N_ * P_) / 4;
    const int cpx = nwg >> 3;
    const int bid = blockIdx.x;
    const int swz = (bid & 7) * cpx + (bid >> 3);
    const int slot = (swz << 2) + (threadIdx.x >> 6);
    const int n    = __builtin_amdgcn_readfirstlane(order[slot >> 5]);
    const int p    = slot & (P_ - 1);
    const int lane = threadIdx.x & 63;
    process_bin(feat, boxes, batch_idx, out, nullptr, 0, 0, (n << 5) | p, lane);
}
// ---------------------------------------------------------------------------

extern "C" void kernel_launch(void* const* d_in, const int* in_sizes, int n_in,
                              void* d_out, int out_size, void* d_ws, size_t ws_size,
                              hipStream_t stream) {
    const float* feat      = (const float*)d_in[0];
    const float* boxes     = (const float*)d_in[1];
    const int*   batch_idx = (const int*)d_in[2];
    float*       out       = (float*)d_out;

    const size_t need = (size_t)(1024 + NWIN_ * CAP_ + NBINS_) * sizeof(int); // ~772 KB
    if (ws_size >= need) {
        int* wsp = (int*)d_ws;
        hipMemsetAsync(wsp, 0, (NWIN_ + 1) * sizeof(int), stream);   // cnt + ovfc
        scatter_bins_kernel<<<NBINS_ / 256, 256, 0, stream>>>(boxes, batch_idx, wsp);
        roi_win_kernel<<<NGW_ + NOVF_, 512, 0, stream>>>(feat, boxes, batch_idx, wsp, out);
    } else {                                             // fallback: R5 path
        int* order = (int*)d_ws;                         // 8 KB
        build_order_kernel<<<1, 256, 0, stream>>>(batch_idx, order);
        roi_rows_kernel<<<(N_ * P_) / 4, 256, 0, stream>>>(feat, boxes, batch_idx, order, out);
    }
}

// Round 9
// 203.617 us; speedup vs baseline: 1.0911x; 1.0911x over previous
//
#include <hip/hip_runtime.h>

#define B_     8
#define LV_    4096
#define D_     256
#define N_     2048
#define P_     32
#define WROWS_ 64                      // rows per LDS window (64 KB tile)
#define SEGS_  4                       // segments per window
#define NWIN_  (B_ * (LV_ / WROWS_))   // 512 windows
#define NBLK_  (NWIN_ * SEGS_)         // 2048 blocks == R7's proven shape

typedef float v4f __attribute__((ext_vector_type(4)));

__device__ __forceinline__ float lane_bcast_f(float v, int l) {
    return __int_as_float(__builtin_amdgcn_readlane(__float_as_int(v), l));
}

// First row touched by bin (n,p) — same clamping as the main math. Monotone
// nondecreasing in p (boff and a are nondecreasing; floor+clamp preserve it),
// so a box's bins inside one window form a CONTIGUOUS p-interval.
__device__ __forceinline__ int bin_r_first(const float* __restrict__ boxes, int n, int p) {
    const float y1 = boxes[2 * n], y2 = boxes[2 * n + 1];
    const float bin_h = (y2 - y1) * (1.0f / (float)P_);
    const int gh = (int)ceilf(bin_h);
    if (gh < 1) return 0;
    const float sub  = bin_h / (float)gh;
    const float boff = (y1 - 0.5f) + (float)p * bin_h;
    const float a    = fmaf(0.5f, sub, boff);
    int r = (int)floorf(a);
    if (r < 0) r = 0;
    if (r > LV_ - 1) r = LV_ - 1;
    return r;
}

// Pass 1: counting-sort boxes by batch into order[] + batch offsets offs[9].
// ~3us, single tiny block — the ONLY pre-pass (R7's 4-dispatch sort chain
// cost ~40us of launch tax; R8's bucket scatter ~20us; this is ~3).
__global__ __launch_bounds__(256) void build_order_kernel(
    const int* __restrict__ batch_idx, int* __restrict__ order, int* __restrict__ offs)
{
    __shared__ int cnt[B_], cur[B_];
    const int tid = threadIdx.x;
    if (tid < B_) cnt[tid] = 0;
    __syncthreads();
    for (int n = tid; n < N_; n += 256) atomicAdd(&cnt[batch_idx[n]], 1);
    __syncthreads();
    if (tid == 0) {
        int s = 0;
        for (int b = 0; b < B_; ++b) { cur[b] = s; offs[b] = s; s += cnt[b]; }
        offs[B_] = s;
    }
    __syncthreads();
    for (int n = tid; n < N_; n += 256)
        order[atomicAdd(&cur[batch_idx[n]], 1)] = n;
}

// Per-bin accumulation: identical math to R5/R7/R8 (same absmax). Rows in
// [wlo, wlo+WROWS_) come from the LDS tile, others from global.
__device__ __forceinline__ void process_bin(
    const float* __restrict__ feat, const float* __restrict__ boxes,
    const int* __restrict__ batch_idx, float* __restrict__ out,
    const v4f* tile, int wb, int wlo, int idx, int lane)
{
    const int n = idx >> 5, p = idx & 31;
    const int bi = __builtin_amdgcn_readfirstlane(batch_idx[n]);

    const float y1 = boxes[2 * n], y2 = boxes[2 * n + 1];
    const float bin_h = (y2 - y1) * (1.0f / (float)P_);
    const int gh = (int)ceilf(bin_h);

    const v4f* prow = (const v4f*)feat + (long)bi * (LV_ * (D_ / 4));
    v4f acc0 = {0.f,0.f,0.f,0.f}, acc1 = {0.f,0.f,0.f,0.f};

    if (gh >= 1) {
        const float cntf = (float)gh, sub = bin_h / cntf, inv_sub = 1.0f / sub;
        const float halfsub = 0.5f * sub;
        const float boff = (y1 - 0.5f) + (float)p * bin_h;
        const float a = fmaf(0.5f, sub, boff), ylast = fmaf(cntf - 0.5f, sub, boff);

        int r_first = (int)floorf(a);
        if (r_first < 0) r_first = 0; if (r_first > LV_-1) r_first = LV_-1;
        int r_last = (int)floorf(ylast) + 1;
        if (r_last > LV_-1) r_last = LV_-1; if (r_last < r_first) r_last = r_first;
        const int r0 = __builtin_amdgcn_readfirstlane(r_first);
        const int rl = __builtin_amdgcn_readfirstlane(r_last);
        const float lanef = (float)lane;

        for (int gbase = r0; gbase <= rl; gbase += 64) {
            int kmax = rl - gbase; if (kmax > 63) kmax = 63;

            // lane-parallel closed-form weights (2nd difference of prefix area)
            const int   r  = gbase + lane;
            const float d0 = ((float)gbase + lanef) - a;
            const float dm = d0 - 1.0f, dp = d0 + 1.0f;
            const float nm = fminf(fmaxf(ceilf(dm * inv_sub), 0.0f), cntf);
            const float n0 = fminf(fmaxf(ceilf(d0 * inv_sub), 0.0f), cntf);
            const float np = fminf(fmaxf(ceilf(dp * inv_sub), 0.0f), cntf);
            float Pm = fmaf(nm, dm, -halfsub * fmaf(nm, nm, -nm));
            float P0 = fmaf(n0, d0, -halfsub * fmaf(n0, n0, -n0));
            float Pp = fmaf(np, dp, -halfsub * fmaf(np, np, -np));
            if (r == 0)       Pm = P0;
            if (r == LV_ - 1) Pp = P0 + cntf;
            const float Wl = (Pm + Pp) - 2.0f * P0;

            // split k-range into [0,lo) global | [lo,hi) LDS | [hi,t) global
            const int t = kmax + 1;
            int lo, hi;
            if (tile && bi == wb) {
                lo = wlo - gbase;          lo = lo < 0 ? 0 : (lo > t ? t : lo);
                hi = wlo + WROWS_ - gbase; hi = hi < lo ? lo : (hi > t ? t : hi);
            } else { lo = t; hi = t; }

#define GSEG(KS, KE) do {                                                        \
    int k = (KS);                                                                \
    const v4f* pS = prow + (long)(gbase + k) * (D_ / 4);                         \
    for (; k + 4 <= (KE); k += 4) {                                              \
        v4f v0 = pS[lane], v1 = pS[lane+64], v2 = pS[lane+128], v3 = pS[lane+192];\
        acc0 += v0 * lane_bcast_f(Wl, k);   acc1 += v1 * lane_bcast_f(Wl, k+1);  \
        acc0 += v2 * lane_bcast_f(Wl, k+2); acc1 += v3 * lane_bcast_f(Wl, k+3);  \
        pS += 4 * (D_ / 4); }                                                    \
    for (; k < (KE); ++k) { v4f v = pS[lane]; acc0 += v * lane_bcast_f(Wl, k); pS += (D_ / 4); } \
} while (0)

            GSEG(0, lo);                               // prefix (usually empty)
            {                                          // LDS mid-segment
                int k = lo;
                const v4f* tp = tile + (gbase + lo - wlo) * 64 + lane;
                for (; k + 4 <= hi; k += 4) {
                    v4f t0 = tp[0], t1 = tp[64], t2 = tp[128], t3 = tp[192];
                    acc0 += t0 * lane_bcast_f(Wl, k);   acc1 += t1 * lane_bcast_f(Wl, k+1);
                    acc0 += t2 * lane_bcast_f(Wl, k+2); acc1 += t3 * lane_bcast_f(Wl, k+3);
                    tp += 256;
                }
                for (; k < hi; ++k) { acc0 += tp[0] * lane_bcast_f(Wl, k); tp += 64; }
            }
            GSEG(hi, t);                               // suffix overhang
#undef GSEG
        }
    }

    const float inv_c = 1.0f / (float)(gh > 1 ? gh : 1);
    v4f res = (acc0 + acc1) * inv_c;
    v4f* op = (v4f*)out + ((long)n * P_ + p) * (D_ / 4) + lane;
    __builtin_nontemporal_store(res, op);
}

// Main kernel: block = (window w, seg). NO materialized bin list: each wave
// streams every-32nd box of the window's batch, derives the contiguous
// p-interval of bins owned by this window (conservative closed-form range,
// then EXACT lane-parallel bin_r_first test + ballot), and runs process_bin
// per hit. Ownership: window containing r_first -> each bin done exactly once.
__global__ __launch_bounds__(512) void roi_win_kernel(
    const float* __restrict__ feat, const float* __restrict__ boxes,
    const int* __restrict__ batch_idx, const int* __restrict__ order,
    const int* __restrict__ offs, float* __restrict__ out)
{
    __shared__ v4f tile[WROWS_ * 64];                  // 64 KB -> 2 blocks/CU
    __shared__ int flag;

    const int tid  = threadIdx.x;
    const int lane = tid & 63;
    const int wv   = tid >> 6;                         // wave 0..7
    const int bid  = blockIdx.x;

    // bijective XCD swizzle: XCD x -> blk [256x,256x+256) -> w [64x,64x+64)
    // -> exactly batch x, resident in its own 4MB L2.
    const int blk = (bid & 7) * (NBLK_ / 8) + (bid >> 3);
    const int w   = blk >> 2;                          // window id
    const int seg = blk & (SEGS_ - 1);
    const int wb  = w >> 6;                            // batch
    const int wt  = w & 63;                            // window index in batch
    const int wlo = wt << 6;                           // first row of window

    const int off_b = offs[wb];
    const int cnt_b = offs[wb + 1] - off_b;

    // ---- cheap conservative emptiness check (before staging!) ----
    // hit=false => no p of box n has r_first in window (monotonicity) => safe.
    if (tid == 0) flag = 0;
    __syncthreads();
    for (int jj = tid; jj < cnt_b; jj += 512) {
        const int n = order[off_b + jj];
        const int rlo = bin_r_first(boxes, n, 0);
        const int rhi = bin_r_first(boxes, n, P_ - 1);
        if (rlo < wlo + WROWS_ && rhi >= wlo) { flag = 1; break; }
    }
    __syncthreads();
    if (!flag) return;

    // ---- stage window: 8 waves x 8 rows, direct global->LDS (lane*16B) ----
    {
        const int r0 = wv * 8;
        const float* srow = feat + ((long)wb * LV_ + wlo + r0) * D_ + lane * 4;
        v4f* lrow = tile + r0 * 64;
#if __has_builtin(__builtin_amdgcn_global_load_lds)
        #pragma unroll
        for (int j = 0; j < 8; ++j) {
            __builtin_amdgcn_global_load_lds(
                (const __attribute__((address_space(1))) void*)(srow + j * D_),
                (__attribute__((address_space(3))) void*)(lrow + j * 64),
                16, 0, 0);
        }
#else
        const v4f* src = (const v4f*)feat + ((long)wb * LV_ + wlo + r0) * (D_ / 4) + lane;
        v4f t0 = src[0],   t1 = src[64],  t2 = src[128], t3 = src[192];
        v4f t4 = src[256], t5 = src[320], t6 = src[384], t7 = src[448];
        v4f* dst = lrow + lane;
        dst[0]   = t0; dst[64]  = t1; dst[128] = t2; dst[192] = t3;
        dst[256] = t4; dst[320] = t5; dst[384] = t6; dst[448] = t7;
#endif
    }
    __syncthreads();                                   // drains vmcnt+lgkmcnt

    // ---- process: each wave streams boxes j = seg + 4*wv + 32*t ----
    for (int j = seg + SEGS_ * wv; j < cnt_b; j += SEGS_ * 8) {
        const int n = __builtin_amdgcn_readfirstlane(order[off_b + j]);

        const float y1 = boxes[2 * n], y2 = boxes[2 * n + 1];
        const float bin_h = (y2 - y1) * (1.0f / (float)P_);
        const int gh = (int)ceilf(bin_h);

        // conservative candidate p-range (exact test below is the arbiter)
        int pl_c, width;
        if (bin_h > 1e-6f) {
            const float sub   = bin_h / (float)(gh < 1 ? 1 : gh);
            const float A0    = (y1 - 0.5f) + 0.5f * sub;      // a(p) = A0 + p*bin_h
            const float invbh = 1.0f / bin_h;
            const float plf = (wt == 0)  ? 0.0f  : ((float)wlo - A0) * invbh - 1.0f;
            const float phf = (wt == 63) ? 32.0f : ((float)(wlo + WROWS_) - A0) * invbh + 1.0f;
            int pl = (int)floorf(fminf(fmaxf(plf, 0.0f), 32.0f));
            int ph = (int)ceilf(fminf(fmaxf(phf, 0.0f), 32.0f));
            if (ph < pl) ph = pl;
            pl_c = pl; width = ph - pl;
        } else {                                       // degenerate: test all p
            pl_c = 0; width = 32;
        }
        if (width == 0) continue;

        // exact lane-parallel ownership test, one candidate p per lane
        bool in = false;
        if (lane < width) {
            const int p = pl_c + lane;                 // < 32 by construction
            in = ((bin_r_first(boxes, n, p) >> 6) == wt);
        }
        const unsigned long long m = __ballot(in);
        if (!m) continue;
        const int pl   = pl_c + __builtin_ctzll(m);    // contiguous run (monotone)
        const int pcnt = __builtin_popcountll(m);

        for (int pp = pl; pp < pl + pcnt; ++pp)
            process_bin(feat, boxes, batch_idx, out, tile, wb, wlo, (n << 5) | pp, lane);
    }
}

// Emergency fallback (workspace too small): direct global-path kernel.
__global__ __launch_bounds__(256) void roi_plain_kernel(
    const float* __restrict__ feat, const float* __restrict__ boxes,
    const int* __restrict__ batch_idx, float* __restrict__ out)
{
    const int slot = blockIdx.x * 4 + (threadIdx.x >> 6);
    const int lane = threadIdx.x & 63;
    process_bin(feat, boxes, batch_idx, out, nullptr, 0, 0, slot, lane);
}

extern "C" void kernel_launch(void* const* d_in, const int* in_sizes, int n_in,
                              void* d_out, int out_size, void* d_ws, size_t ws_size,
                              hipStream_t stream) {
    const float* feat      = (const float*)d_in[0];
    const float* boxes     = (const float*)d_in[1];
    const int*   batch_idx = (const int*)d_in[2];
    float*       out       = (float*)d_out;

    if (ws_size >= (size_t)(N_ + B_ + 1) * sizeof(int)) {
        int* order = (int*)d_ws;                       // [N_]
        int* offs  = order + N_;                       // [B_+1]
        build_order_kernel<<<1, 256, 0, stream>>>(batch_idx, order, offs);
        roi_win_kernel<<<NBLK_, 512, 0, stream>>>(feat, boxes, batch_idx, order, offs, out);
    } else {
        roi_plain_kernel<<<(N_ * P_) / 4, 256, 0, stream>>>(feat, boxes, batch_idx, out);
    }
}